// Round 5
// baseline (364.739 us; speedup 1.0000x reference)
//
#include <hip/hip_runtime.h>

#define NB 8
#define NS 2048
#define NH 768
#define NPOS (NB*NS)

typedef short short8 __attribute__((ext_vector_type(8)));
typedef float floatx4 __attribute__((ext_vector_type(4)));

// pack bf16-truncations of two fp32 into one dword: low short=hi(b0), high short=hi(b1)
__device__ __forceinline__ unsigned pack_bf16(unsigned b0, unsigned b1) {
  return __builtin_amdgcn_perm(b1, b0, 0x07060302u);
}

// async global->LDS, 16B per lane; LDS dest must be wave-uniform base + lane*16
#define GLOAD_LDS16(gp, lp) __builtin_amdgcn_global_load_lds( \
  (const __attribute__((address_space(1))) unsigned int*)(gp), \
  (__attribute__((address_space(3))) unsigned int*)(lp), 16, 0, 0)

// ---------------- Kernel A: build V = U * diag((-i)^popcount(j)) ----------------
__global__ void build_V_kernel(const float* __restrict__ wts,
                               float* __restrict__ Vre, float* __restrict__ Vim) {
  int j = threadIdx.x;
  if (j >= 16) return;
  float ar[16], ai[16];
#pragma unroll
  for (int i = 0; i < 16; i++) { ar[i] = (i == j) ? 1.f : 0.f; ai[i] = 0.f; }
#pragma unroll
  for (int l = 0; l < 2; l++) {
#pragma unroll
    for (int q = 0; q < 4; q++) {
      float phi = wts[(l*4+q)*3+0];
      float th  = wts[(l*4+q)*3+1];
      float om  = wts[(l*4+q)*3+2];
      float ct = cosf(0.5f*th), st = sinf(0.5f*th);
      float sm = 0.5f*(phi+om), df = 0.5f*(phi-om);
      float cs = cosf(sm), ss = sinf(sm), cd = cosf(df), sd = sinf(df);
      float Ar =  cs*ct, Ai = -ss*ct;
      float Br = -cd*st, Bi = -sd*st;
      float Cr =  cd*st, Ci = -sd*st;
      float Dr =  cs*ct, Di =  ss*ct;
      int pb = 1 << (3-q);
#pragma unroll
      for (int b0 = 0; b0 < 16; b0++) {
        if (b0 & pb) continue;
        int b1 = b0 | pb;
        float xr = ar[b0], xi = ai[b0], yr = ar[b1], yi = ai[b1];
        ar[b0] = Ar*xr - Ai*xi + Br*yr - Bi*yi;
        ai[b0] = Ar*xi + Ai*xr + Br*yi + Bi*yr;
        ar[b1] = Cr*xr - Ci*xi + Dr*yr - Di*yi;
        ai[b1] = Cr*xi + Ci*xr + Dr*yi + Di*yr;
      }
    }
    const int r = (l == 0) ? 1 : 2;
#pragma unroll
    for (int i2 = 0; i2 < 4; i2++) {
      int cb = 1 << (3-i2);
      int tb = 1 << (3-((i2+r)&3));
#pragma unroll
      for (int b0 = 0; b0 < 16; b0++) {
        if ((b0 & cb) && !(b0 & tb)) {
          int b1 = b0 | tb;
          float tr = ar[b0], ti = ai[b0];
          ar[b0] = ar[b1]; ai[b0] = ai[b1];
          ar[b1] = tr;     ai[b1] = ti;
        }
      }
    }
  }
  int pc = __popc((unsigned)j) & 3;
#pragma unroll
  for (int i = 0; i < 16; i++) {
    float vr = ar[i], vi = ai[i], orr, oi;
    if      (pc == 0) { orr =  vr; oi =  vi; }
    else if (pc == 1) { orr =  vi; oi = -vr; }
    else if (pc == 2) { orr = -vr; oi = -vi; }
    else              { orr = -vi; oi =  vr; }
    Vre[i*16+j] = orr;
    Vim[i*16+j] = oi;
  }
}

// ---------------- Kernel B: Q/K projection + VQC evaluation ----------------
__global__ __launch_bounds__(256) void proj_vqc_kernel(
    const float* __restrict__ E, const float* __restrict__ Wq, const float* __restrict__ bq,
    const float* __restrict__ Wk, const float* __restrict__ bk,
    const float* __restrict__ Vre, const float* __restrict__ Vim,
    float* __restrict__ Qv, float* __restrict__ Kv) {
  __shared__ __align__(16) float WqL[768*4];
  __shared__ __align__(16) float WkL[768*4];
  __shared__ float Vsh[2][16*17];
  int tid = threadIdx.x;
  for (int idx = tid; idx < 768*4; idx += 256) {
    int e = idx >> 2, w = idx & 3;
    WqL[e*4+w] = Wq[w*768+e];
    WkL[e*4+w] = Wk[w*768+e];
  }
  if (tid < 256) {
    int i = tid >> 4, jj = tid & 15;
    Vsh[0][i*17+jj] = Vre[tid];
    Vsh[1][i*17+jj] = Vim[tid];
  }
  __syncthreads();
  float bqr0=bq[0], bqr1=bq[1], bqr2=bq[2], bqr3=bq[3];
  float bkr0=bk[0], bkr1=bk[1], bkr2=bk[2], bkr3=bk[3];
  int lane = tid & 63;
  int wid  = blockIdx.x*4 + (tid >> 6);
  int nw   = gridDim.x*4;
  int grp  = lane >> 4;
  int i    = lane & 15;
  for (int pos = wid; pos < NPOS; pos += nw) {
    const float* er = E + (size_t)pos*768;
    float pq[4] = {0.f,0.f,0.f,0.f};
    float pk[4] = {0.f,0.f,0.f,0.f};
#pragma unroll
    for (int k2 = 0; k2 < 3; k2++) {
      float4 ev = *(const float4*)(er + lane*4 + 256*k2);
#pragma unroll
      for (int jj = 0; jj < 4; jj++) {
        int e = lane*4 + 256*k2 + jj;
        float evs = (jj==0) ? ev.x : (jj==1) ? ev.y : (jj==2) ? ev.z : ev.w;
        float4 wq4 = *(const float4*)&WqL[e*4];
        float4 wk4 = *(const float4*)&WkL[e*4];
        pq[0] += evs*wq4.x; pq[1] += evs*wq4.y; pq[2] += evs*wq4.z; pq[3] += evs*wq4.w;
        pk[0] += evs*wk4.x; pk[1] += evs*wk4.y; pk[2] += evs*wk4.z; pk[3] += evs*wk4.w;
      }
    }
    float part[8];
#pragma unroll
    for (int w = 0; w < 8; w++) {
      float v = (w < 4) ? pq[w] : pk[w-4];
      v += __shfl_xor(v, 32); v += __shfl_xor(v, 16); v += __shfl_xor(v, 8);
      v += __shfl_xor(v, 4);  v += __shfl_xor(v, 2);  v += __shfl_xor(v, 1);
      part[w] = v;
    }
    if (grp < 2) {
      float a0,a1,a2,a3;
      if (grp == 0) { a0=part[0]+bqr0; a1=part[1]+bqr1; a2=part[2]+bqr2; a3=part[3]+bqr3; }
      else          { a0=part[4]+bkr0; a1=part[5]+bkr1; a2=part[6]+bkr2; a3=part[7]+bkr3; }
      float c0=cosf(0.5f*a0), s0=sinf(0.5f*a0);
      float c1=cosf(0.5f*a1), s1=sinf(0.5f*a1);
      float c2=cosf(0.5f*a2), s2=sinf(0.5f*a2);
      float c3=cosf(0.5f*a3), s3=sinf(0.5f*a3);
      float m[16];
#pragma unroll
      for (int j2 = 0; j2 < 16; j2++) {
        float f0 = (j2 & 8) ? s0 : c0;
        float f1 = (j2 & 4) ? s1 : c1;
        float f2 = (j2 & 2) ? s2 : c2;
        float f3 = (j2 & 1) ? s3 : c3;
        m[j2] = f0*f1*f2*f3;
      }
      float re = 0.f, im = 0.f;
#pragma unroll
      for (int j2 = 0; j2 < 16; j2++) {
        re += Vsh[0][i*17+j2]*m[j2];
        im += Vsh[1][i*17+j2]*m[j2];
      }
      float pr = re*re + im*im;
      float r0 = (i & 8) ? -pr : pr;
      float r1 = (i & 4) ? -pr : pr;
      float r2 = (i & 2) ? -pr : pr;
      float r3 = (i & 1) ? -pr : pr;
#pragma unroll
      for (int off = 8; off >= 1; off >>= 1) {
        r0 += __shfl_xor(r0, off);
        r1 += __shfl_xor(r1, off);
        r2 += __shfl_xor(r2, off);
        r3 += __shfl_xor(r3, off);
      }
      if (i == 0) {
        float* dst = (grp == 0 ? Qv : Kv) + (size_t)pos*4;
        dst[0]=r0; dst[1]=r1; dst[2]=r2; dst[3]=r3;
      }
    }
  }
}

// ---------------- Kernel Epre: pre-tile E into swizzled bf16 hi/lo tiles ----------------
// Tile (b, hb, tc) = [128 h][32 t], 4096 shorts (8 KB), swizzled LDS image:
// off = h2*32 + (q2^((h2>>1)&3))*8.
__global__ __launch_bounds__(256) void epre_kernel(
    const float* __restrict__ E, unsigned short* __restrict__ EhiT,
    unsigned short* __restrict__ EloT) {
  int tc = blockIdx.x, hb = blockIdx.y, b = blockIdx.z;
  size_t tbase = ((size_t)((b*6 + hb)*64 + tc)) * 4096;
  const float* Eb = E + (size_t)b*NS*NH + (size_t)tc*32*NH + hb*128;
  int tid = threadIdx.x;
#pragma unroll
  for (int u = 0; u < 2; u++) {
    int unit = tid + 256*u;
    int h2 = unit & 127, q2 = unit >> 7;
    unsigned hi4[4], lo4[4];
#pragma unroll
    for (int jp = 0; jp < 4; jp++) {
      float ea = Eb[(size_t)(q2*8 + 2*jp    )*NH + h2];
      float eb = Eb[(size_t)(q2*8 + 2*jp + 1)*NH + h2];
      unsigned ba = __float_as_uint(ea), bb = __float_as_uint(eb);
      float la = ea - __uint_as_float(ba & 0xFFFF0000u);
      float lb = eb - __uint_as_float(bb & 0xFFFF0000u);
      hi4[jp] = pack_bf16(ba, bb);
      lo4[jp] = pack_bf16(__float_as_uint(la), __float_as_uint(lb));
    }
    int off = h2*32 + ((q2 ^ ((h2>>1)&3))*8);
    *(uint4*)&EhiT[tbase + off] = make_uint4(hi4[0],hi4[1],hi4[2],hi4[3]);
    *(uint4*)&EloT[tbase + off] = make_uint4(lo4[0],lo4[1],lo4[2],lo4[3]);
  }
}

// ---------------- Kernel Pgen: P = exp(Qv.Kv^T) hi/lo tiles + denominators ----------------
// Tile (b, sblk, tc) = [128 s][32 t] A-layout image: off = s*32 + (c^((s>>1)&3))*8.
// Block = (tq, sblk, b): 8 tiles (tc = tq*8 .. +7). den accumulated via atomics
// from exact fp32 p (numerics identical to round-4 in-attn P-gen).
__global__ __launch_bounds__(256) void pgen_kernel(
    const float* __restrict__ Qv, const float* __restrict__ Kv,
    unsigned short* __restrict__ PhiT, unsigned short* __restrict__ PloT,
    float* __restrict__ den) {
  int tq = blockIdx.x, sblk = blockIdx.y, b = blockIdx.z;
  int tid = threadIdx.x;
  __shared__ __align__(16) float kvl[256*4];   // 4 KB, 16B-line xor-swizzled
  {
    const float4 v = ((const float4*)(Kv + ((size_t)b*NS + tq*256)*4))[tid];
    ((float4*)kvl)[tid ^ ((tid >> 3) & 3)] = v;
  }
  int s0 = tid >> 2, c = tid & 3;
  const float* Qb = Qv + ((size_t)b*NS + sblk*128)*4;
  float4 qv0 = *(const float4*)&Qb[s0*4];
  float4 qv1 = *(const float4*)&Qb[(64+s0)*4];
  __syncthreads();
  float den0 = 0.f, den1 = 0.f;
  size_t tb = ((size_t)((b*16 + sblk)*64) + tq*8) * 4096;
  int off0 = s0*32 + ((c ^ ((s0>>1)&3))*8);
  int off1 = (64+s0)*32 + ((c ^ (((64+s0)>>1)&3))*8);
#pragma unroll 2
  for (int tt = 0; tt < 8; tt++) {
#pragma unroll
    for (int r = 0; r < 2; r++) {
      float4 qv = r ? qv1 : qv0;
      unsigned hi4[4], lo4[4];
      float dsum = 0.f;
#pragma unroll
      for (int jp = 0; jp < 4; jp++) {
        int La = tt*32 + c*8 + 2*jp;
        float4 ka = ((const float4*)kvl)[La ^ c];
        float4 kb = ((const float4*)kvl)[(La+1) ^ c];
        float arga = qv.x*ka.x + qv.y*ka.y + qv.z*ka.z + qv.w*ka.w;
        float argb = qv.x*kb.x + qv.y*kb.y + qv.z*kb.z + qv.w*kb.w;
        float pa = __expf(arga), pb = __expf(argb);
        dsum += pa + pb;
        unsigned bpa = __float_as_uint(pa), bpb = __float_as_uint(pb);
        float lpa = pa - __uint_as_float(bpa & 0xFFFF0000u);
        float lpb = pb - __uint_as_float(bpb & 0xFFFF0000u);
        hi4[jp] = pack_bf16(bpa, bpb);
        lo4[jp] = pack_bf16(__float_as_uint(lpa), __float_as_uint(lpb));
      }
      if (r) den1 += dsum; else den0 += dsum;
      size_t base = tb + (size_t)tt*4096 + (r ? off1 : off0);
      *(uint4*)&PhiT[base] = make_uint4(hi4[0],hi4[1],hi4[2],hi4[3]);
      *(uint4*)&PloT[base] = make_uint4(lo4[0],lo4[1],lo4[2],lo4[3]);
    }
  }
  atomicAdd(&den[(size_t)b*NS + sblk*128 + s0], den0);
  atomicAdd(&den[(size_t)b*NS + sblk*128 + 64 + s0], den1);
}

// ---------------- Kernel C: attention GEMM — all tiles DMA'd, pure MFMA loop ----------------
// 128 s x 128 h per block, chunks of 32 t. A (P) single-buffered + read-to-regs
// before 2nd barrier; B (E) double-buffered. 48 KB LDS -> 3 blocks/CU (all 768
// blocks resident). 3-pass split-bf16 MFMA (ah*bl + al*bh + ah*bh).
#define TKC 32

__global__ __launch_bounds__(256, 3) void attn_kernel(
    const unsigned short* __restrict__ PhiT, const unsigned short* __restrict__ PloT,
    const unsigned short* __restrict__ EhiT, const unsigned short* __restrict__ EloT,
    const float* __restrict__ den, float* __restrict__ out) {
  int hblk = blockIdx.x;   // 0..5
  int sblk = blockIdx.y;   // 0..15
  int b    = blockIdx.z;   // 0..7
  int tid  = threadIdx.x;
  int lane = tid & 63;
  int w    = tid >> 6;

  __shared__ __align__(16) unsigned short sAhi[128*TKC];      // 8 KB
  __shared__ __align__(16) unsigned short sAlo[128*TKC];      // 8 KB
  __shared__ __align__(16) unsigned short sBhi[2][128*TKC];   // 16 KB
  __shared__ __align__(16) unsigned short sBlo[2][128*TKC];   // 16 KB

  const unsigned short* pHi = PhiT + ((size_t)(b*16 + sblk)*64) * 4096;
  const unsigned short* pLo = PloT + ((size_t)(b*16 + sblk)*64) * 4096;
  const unsigned short* tHi = EhiT + ((size_t)(b*6 + hblk)*64) * 4096;
  const unsigned short* tLo = EloT + ((size_t)(b*6 + hblk)*64) * 4096;

  int sh = w & 1, hh = w >> 1;
  floatx4 acc[4][4];
#pragma unroll
  for (int i = 0; i < 4; i++)
#pragma unroll
    for (int jt = 0; jt < 4; jt++) acc[i][jt] = floatx4{0.f,0.f,0.f,0.f};

  int m16 = lane & 15, q16 = lane >> 4;
  int cidx = (q16 ^ ((m16 >> 1) & 3)) * 8;   // swizzled chunk offset for frag reads
  int t16 = tid * 8;                          // DMA: 16 B per thread

  // prologue: DMA chunk 0 (A into sA, B into sB[0])
  GLOAD_LDS16(pHi + t16,        &sAhi[t16]);
  GLOAD_LDS16(pHi + 2048 + t16, &sAhi[2048 + t16]);
  GLOAD_LDS16(pLo + t16,        &sAlo[t16]);
  GLOAD_LDS16(pLo + 2048 + t16, &sAlo[2048 + t16]);
  GLOAD_LDS16(tHi + t16,        &sBhi[0][t16]);
  GLOAD_LDS16(tHi + 2048 + t16, &sBhi[0][2048 + t16]);
  GLOAD_LDS16(tLo + t16,        &sBlo[0][t16]);
  GLOAD_LDS16(tLo + 2048 + t16, &sBlo[0][2048 + t16]);

  for (int tc = 0; tc < NS; tc += TKC) {
    int ci = tc >> 5;
    int cb = ci & 1;
    __syncthreads();   // barrier 1: DMA for chunk ci drained everywhere

    // --- read A frags to registers (sA reused next iter) ---
    short8 ah[4], al[4];
#pragma unroll
    for (int i = 0; i < 4; i++) {
      int srow = sh*64 + i*16 + m16;
      ah[i] = __builtin_bit_cast(short8, *(const uint4*)&sAhi[srow*TKC + cidx]);
      al[i] = __builtin_bit_cast(short8, *(const uint4*)&sAlo[srow*TKC + cidx]);
    }
    __syncthreads();   // barrier 2: all waves' A reads complete -> sA reusable

    // --- DMA next chunk (A -> sA, B -> sB[cb^1]); drains at next barrier 1 ---
    if (tc + TKC < NS) {
      const unsigned short* npHi = pHi + (size_t)(ci+1)*4096;
      const unsigned short* npLo = pLo + (size_t)(ci+1)*4096;
      const unsigned short* ntHi = tHi + (size_t)(ci+1)*4096;
      const unsigned short* ntLo = tLo + (size_t)(ci+1)*4096;
      int nb = cb ^ 1;
      GLOAD_LDS16(npHi + t16,        &sAhi[t16]);
      GLOAD_LDS16(npHi + 2048 + t16, &sAhi[2048 + t16]);
      GLOAD_LDS16(npLo + t16,        &sAlo[t16]);
      GLOAD_LDS16(npLo + 2048 + t16, &sAlo[2048 + t16]);
      GLOAD_LDS16(ntHi + t16,        &sBhi[nb][t16]);
      GLOAD_LDS16(ntHi + 2048 + t16, &sBhi[nb][2048 + t16]);
      GLOAD_LDS16(ntLo + t16,        &sBlo[nb][t16]);
      GLOAD_LDS16(ntLo + 2048 + t16, &sBlo[nb][2048 + t16]);
    }

    // --- B frags + 48 MFMA ---
#pragma unroll
    for (int jt = 0; jt < 4; jt++) {
      int hrow = hh*64 + jt*16 + m16;
      short8 bh_ = __builtin_bit_cast(short8, *(const uint4*)&sBhi[cb][hrow*TKC + cidx]);
      short8 bl_ = __builtin_bit_cast(short8, *(const uint4*)&sBlo[cb][hrow*TKC + cidx]);
#pragma unroll
      for (int i = 0; i < 4; i++) {
        acc[i][jt] = __builtin_amdgcn_mfma_f32_16x16x32_bf16(ah[i], bl_, acc[i][jt], 0, 0, 0);
        acc[i][jt] = __builtin_amdgcn_mfma_f32_16x16x32_bf16(al[i], bh_, acc[i][jt], 0, 0, 0);
        acc[i][jt] = __builtin_amdgcn_mfma_f32_16x16x32_bf16(ah[i], bh_, acc[i][jt], 0, 0, 0);
      }
    }
  }

  // --- epilogue: C/D layout col=lane&15, row=(lane>>4)*4+reg; scale by 1/den ---
  const float* den_g = den + (size_t)b*NS + sblk*128;
  float* ob = out + ((size_t)(b*NS + sblk*128))*NH + hblk*128;
#pragma unroll
  for (int i = 0; i < 4; i++) {
#pragma unroll
    for (int reg = 0; reg < 4; reg++) {
      int row = q16*4 + reg;
      int s_loc = sh*64 + i*16 + row;
      float invd = 1.0f / den_g[s_loc];
#pragma unroll
      for (int jt = 0; jt < 4; jt++) {
        int h_loc = hh*64 + jt*16 + m16;
        ob[(size_t)s_loc*NH + h_loc] = acc[i][jt][reg] * invd;
      }
    }
  }
}

extern "C" void kernel_launch(void* const* d_in, const int* in_sizes, int n_in,
                              void* d_out, int out_size, void* d_ws, size_t ws_size,
                              hipStream_t stream) {
  const float* E   = (const float*)d_in[0];
  const float* Wq  = (const float*)d_in[1];
  const float* bq  = (const float*)d_in[2];
  const float* Wk  = (const float*)d_in[3];
  const float* bk  = (const float*)d_in[4];
  const float* wts = (const float*)d_in[5];
  float* ws  = (float*)d_ws;
  float* Vre = ws;                       // 256 f
  float* Vim = ws + 256;                 // 256 f
  float* Qv  = ws + 512;                 // NPOS*4 f
  float* Kv  = Qv + (size_t)NPOS*4;      // NPOS*4 f
  float* den = Kv + (size_t)NPOS*4;      // NPOS f
  unsigned short* EhiT = (unsigned short*)(den + NPOS);
  unsigned short* EloT = EhiT + (size_t)NB*6*64*4096;    // 25.2 MB each
  unsigned short* PhiT = EloT + (size_t)NB*6*64*4096;
  unsigned short* PloT = PhiT + (size_t)NB*16*64*4096;   // 67 MB each; ~235 MB total ws
  float* out = (float*)d_out;

  build_V_kernel<<<1, 64, 0, stream>>>(wts, Vre, Vim);
  epre_kernel<<<dim3(64, 6, 8), 256, 0, stream>>>(E, EhiT, EloT);
  proj_vqc_kernel<<<1024, 256, 0, stream>>>(E, Wq, bq, Wk, bk, Vre, Vim, Qv, Kv);
  hipMemsetAsync(den, 0, (size_t)NPOS*sizeof(float), stream);
  pgen_kernel<<<dim3(8, 16, 8), 256, 0, stream>>>(Qv, Kv, PhiT, PloT, den);
  attn_kernel<<<dim3(6, 16, 8), 256, 0, stream>>>(PhiT, PloT, EhiT, EloT, den, out);
}

// Round 6
// 285.963 us; speedup vs baseline: 1.2755x; 1.2755x over previous
//
#include <hip/hip_runtime.h>

#define NB 8
#define NS 2048
#define NH 768
#define NPOS (NB*NS)

typedef short short8 __attribute__((ext_vector_type(8)));
typedef float floatx4 __attribute__((ext_vector_type(4)));

// pack bf16-truncations of two fp32 into one dword: low short=hi(b0), high short=hi(b1)
__device__ __forceinline__ unsigned pack_bf16(unsigned b0, unsigned b1) {
  return __builtin_amdgcn_perm(b1, b0, 0x07060302u);
}

// async global->LDS, 16B per lane; LDS dest must be wave-uniform base + lane*16
#define GLOAD_LDS16(gp, lp) __builtin_amdgcn_global_load_lds( \
  (const __attribute__((address_space(1))) unsigned int*)(gp), \
  (__attribute__((address_space(3))) unsigned int*)(lp), 16, 0, 0)

// ---------------- Kernel Epre: pre-tile E into swizzled bf16 hi/lo tiles ----------------
// Tile (b, hb, tc) = [192 h][32 t], 12288 shorts (24 KB): hi image [0,6144),
// lo image [6144,12288); within each: off = h2*32 + ((q2^((h2>>1)&3))*8).
// Block (0,0,0) threads 0..15 additionally build V = U*diag((-i)^popc) (tiny).
__global__ __launch_bounds__(384) void epre_kernel(
    const float* __restrict__ E, const float* __restrict__ wts,
    float* __restrict__ Vre, float* __restrict__ Vim,
    unsigned short* __restrict__ ET) {
  int tc = blockIdx.x, hb = blockIdx.y, b = blockIdx.z;
  int tid = threadIdx.x;

  if (tc == 0 && hb == 0 && b == 0 && tid < 16) {
    int j = tid;
    float ar[16], ai[16];
#pragma unroll
    for (int i = 0; i < 16; i++) { ar[i] = (i == j) ? 1.f : 0.f; ai[i] = 0.f; }
#pragma unroll
    for (int l = 0; l < 2; l++) {
#pragma unroll
      for (int q = 0; q < 4; q++) {
        float phi = wts[(l*4+q)*3+0];
        float th  = wts[(l*4+q)*3+1];
        float om  = wts[(l*4+q)*3+2];
        float ct = cosf(0.5f*th), st = sinf(0.5f*th);
        float sm = 0.5f*(phi+om), df = 0.5f*(phi-om);
        float cs = cosf(sm), ss = sinf(sm), cd = cosf(df), sd = sinf(df);
        float Ar =  cs*ct, Ai = -ss*ct;
        float Br = -cd*st, Bi = -sd*st;
        float Cr =  cd*st, Ci = -sd*st;
        float Dr =  cs*ct, Di =  ss*ct;
        int pb = 1 << (3-q);
#pragma unroll
        for (int b0 = 0; b0 < 16; b0++) {
          if (b0 & pb) continue;
          int b1 = b0 | pb;
          float xr = ar[b0], xi = ai[b0], yr = ar[b1], yi = ai[b1];
          ar[b0] = Ar*xr - Ai*xi + Br*yr - Bi*yi;
          ai[b0] = Ar*xi + Ai*xr + Br*yi + Bi*yr;
          ar[b1] = Cr*xr - Ci*xi + Dr*yr - Di*yi;
          ai[b1] = Cr*xi + Ci*xr + Dr*yi + Di*yr;
        }
      }
      const int r = (l == 0) ? 1 : 2;
#pragma unroll
      for (int i2 = 0; i2 < 4; i2++) {
        int cb = 1 << (3-i2);
        int tb = 1 << (3-((i2+r)&3));
#pragma unroll
        for (int b0 = 0; b0 < 16; b0++) {
          if ((b0 & cb) && !(b0 & tb)) {
            int b1 = b0 | tb;
            float tr = ar[b0], ti = ai[b0];
            ar[b0] = ar[b1]; ai[b0] = ai[b1];
            ar[b1] = tr;     ai[b1] = ti;
          }
        }
      }
    }
    int pc = __popc((unsigned)j) & 3;
#pragma unroll
    for (int i = 0; i < 16; i++) {
      float vr = ar[i], vi = ai[i], orr, oi;
      if      (pc == 0) { orr =  vr; oi =  vi; }
      else if (pc == 1) { orr =  vi; oi = -vr; }
      else if (pc == 2) { orr = -vr; oi = -vi; }
      else              { orr = -vi; oi =  vr; }
      Vre[i*16+j] = orr;
      Vim[i*16+j] = oi;
    }
  }

  size_t tbase = ((size_t)((b*4 + hb)*64 + tc)) * 12288;
  const float* Eb = E + (size_t)b*NS*NH + (size_t)tc*32*NH + hb*192;
#pragma unroll
  for (int u = 0; u < 2; u++) {
    int unit = tid + 384*u;          // 0..767
    int q2 = unit / 192, h2 = unit % 192;
    unsigned hi4[4], lo4[4];
#pragma unroll
    for (int jp = 0; jp < 4; jp++) {
      float ea = Eb[(size_t)(q2*8 + 2*jp    )*NH + h2];
      float eb = Eb[(size_t)(q2*8 + 2*jp + 1)*NH + h2];
      unsigned ba = __float_as_uint(ea), bb = __float_as_uint(eb);
      float la = ea - __uint_as_float(ba & 0xFFFF0000u);
      float lb = eb - __uint_as_float(bb & 0xFFFF0000u);
      hi4[jp] = pack_bf16(ba, bb);
      lo4[jp] = pack_bf16(__float_as_uint(la), __float_as_uint(lb));
    }
    int off = h2*32 + ((q2 ^ ((h2>>1)&3))*8);
    *(uint4*)&ET[tbase + off]        = make_uint4(hi4[0],hi4[1],hi4[2],hi4[3]);
    *(uint4*)&ET[tbase + 6144 + off] = make_uint4(lo4[0],lo4[1],lo4[2],lo4[3]);
  }
}

// ---------------- Kernel B: Q/K projection + VQC evaluation ----------------
__global__ __launch_bounds__(256) void proj_vqc_kernel(
    const float* __restrict__ E, const float* __restrict__ Wq, const float* __restrict__ bq,
    const float* __restrict__ Wk, const float* __restrict__ bk,
    const float* __restrict__ Vre, const float* __restrict__ Vim,
    float* __restrict__ Qv, float* __restrict__ Kv) {
  __shared__ __align__(16) float WqL[768*4];
  __shared__ __align__(16) float WkL[768*4];
  __shared__ float Vsh[2][16*17];
  int tid = threadIdx.x;
  for (int idx = tid; idx < 768*4; idx += 256) {
    int e = idx >> 2, w = idx & 3;
    WqL[e*4+w] = Wq[w*768+e];
    WkL[e*4+w] = Wk[w*768+e];
  }
  if (tid < 256) {
    int i = tid >> 4, jj = tid & 15;
    Vsh[0][i*17+jj] = Vre[tid];
    Vsh[1][i*17+jj] = Vim[tid];
  }
  __syncthreads();
  float bqr0=bq[0], bqr1=bq[1], bqr2=bq[2], bqr3=bq[3];
  float bkr0=bk[0], bkr1=bk[1], bkr2=bk[2], bkr3=bk[3];
  int lane = tid & 63;
  int wid  = blockIdx.x*4 + (tid >> 6);
  int nw   = gridDim.x*4;
  int grp  = lane >> 4;
  int i    = lane & 15;
  for (int pos = wid; pos < NPOS; pos += nw) {
    const float* er = E + (size_t)pos*768;
    float pq[4] = {0.f,0.f,0.f,0.f};
    float pk[4] = {0.f,0.f,0.f,0.f};
#pragma unroll
    for (int k2 = 0; k2 < 3; k2++) {
      float4 ev = *(const float4*)(er + lane*4 + 256*k2);
#pragma unroll
      for (int jj = 0; jj < 4; jj++) {
        int e = lane*4 + 256*k2 + jj;
        float evs = (jj==0) ? ev.x : (jj==1) ? ev.y : (jj==2) ? ev.z : ev.w;
        float4 wq4 = *(const float4*)&WqL[e*4];
        float4 wk4 = *(const float4*)&WkL[e*4];
        pq[0] += evs*wq4.x; pq[1] += evs*wq4.y; pq[2] += evs*wq4.z; pq[3] += evs*wq4.w;
        pk[0] += evs*wk4.x; pk[1] += evs*wk4.y; pk[2] += evs*wk4.z; pk[3] += evs*wk4.w;
      }
    }
    float part[8];
#pragma unroll
    for (int w = 0; w < 8; w++) {
      float v = (w < 4) ? pq[w] : pk[w-4];
      v += __shfl_xor(v, 32); v += __shfl_xor(v, 16); v += __shfl_xor(v, 8);
      v += __shfl_xor(v, 4);  v += __shfl_xor(v, 2);  v += __shfl_xor(v, 1);
      part[w] = v;
    }
    if (grp < 2) {
      float a0,a1,a2,a3;
      if (grp == 0) { a0=part[0]+bqr0; a1=part[1]+bqr1; a2=part[2]+bqr2; a3=part[3]+bqr3; }
      else          { a0=part[4]+bkr0; a1=part[5]+bkr1; a2=part[6]+bkr2; a3=part[7]+bkr3; }
      float c0=cosf(0.5f*a0), s0=sinf(0.5f*a0);
      float c1=cosf(0.5f*a1), s1=sinf(0.5f*a1);
      float c2=cosf(0.5f*a2), s2=sinf(0.5f*a2);
      float c3=cosf(0.5f*a3), s3=sinf(0.5f*a3);
      float m[16];
#pragma unroll
      for (int j2 = 0; j2 < 16; j2++) {
        float f0 = (j2 & 8) ? s0 : c0;
        float f1 = (j2 & 4) ? s1 : c1;
        float f2 = (j2 & 2) ? s2 : c2;
        float f3 = (j2 & 1) ? s3 : c3;
        m[j2] = f0*f1*f2*f3;
      }
      float re = 0.f, im = 0.f;
#pragma unroll
      for (int j2 = 0; j2 < 16; j2++) {
        re += Vsh[0][i*17+j2]*m[j2];
        im += Vsh[1][i*17+j2]*m[j2];
      }
      float pr = re*re + im*im;
      float r0 = (i & 8) ? -pr : pr;
      float r1 = (i & 4) ? -pr : pr;
      float r2 = (i & 2) ? -pr : pr;
      float r3 = (i & 1) ? -pr : pr;
#pragma unroll
      for (int off = 8; off >= 1; off >>= 1) {
        r0 += __shfl_xor(r0, off);
        r1 += __shfl_xor(r1, off);
        r2 += __shfl_xor(r2, off);
        r3 += __shfl_xor(r3, off);
      }
      if (i == 0) {
        float* dst = (grp == 0 ? Qv : Kv) + (size_t)pos*4;
        dst[0]=r0; dst[1]=r1; dst[2]=r2; dst[3]=r3;
      }
    }
  }
}

// ---------------- Kernel C: fused flash attention, 128s x 192h, 8 waves ----------------
// P-gen in-kernel (4x redundancy vs r4's 6x); E tiles DMA'd double-buffered
// from pre-swizzled images; sA single-buffered VALU-written; 3-pass split-bf16
// MFMA; den in registers + one LDS reduce. 67.5 KB LDS -> 2 blocks/CU, 512
// blocks = exactly resident, zero tail.
#define TKC 32

__global__ __launch_bounds__(512, 4) void attn_kernel(
    const unsigned short* __restrict__ ET, const float* __restrict__ Qv,
    const float* __restrict__ Kv, float* __restrict__ out) {
  int sblk = blockIdx.x;   // 0..15
  int hblk = blockIdx.y;   // 0..3
  int b    = blockIdx.z;   // 0..7
  int tid  = threadIdx.x;
  int lane = tid & 63;
  int w    = tid >> 6;     // 0..7

  __shared__ __align__(16) unsigned short sA[8192];       // hi [0,4096), lo [4096,8192)
  __shared__ __align__(16) unsigned short sB[2][12288];   // hi [0,6144), lo [6144,12288)
  __shared__ __align__(16) float kvf[2][TKC][4];
  __shared__ float denp[128*4];
  __shared__ float dfin[128];

  const unsigned short* tE = ET + ((size_t)((b*4 + hblk)*64)) * 12288;
  const float* Kvb = Kv + (size_t)b*NS*4;

  // P-gen mapping: s = tid&127, q-group = tid>>7 (== w>>1, wave-uniform -> kv broadcast)
  int sP = tid & 127, qP = tid >> 7;
  float4 qv = *(const float4*)&Qv[((size_t)(b*NS + sblk*128) + sP)*4];
  float den_acc = 0.f;

  int sh = w & 1, hh = w >> 1;   // wave tile: 64 s x 48 h
  floatx4 acc[4][3];
#pragma unroll
  for (int i = 0; i < 4; i++)
#pragma unroll
    for (int jt = 0; jt < 3; jt++) acc[i][jt] = floatx4{0.f,0.f,0.f,0.f};

  int m16 = lane & 15, q16 = lane >> 4;
  int cidx = (q16 ^ ((m16 >> 1) & 3)) * 8;   // swizzled chunk offset for frag reads
  int t16 = tid * 8;                          // 16 B per thread per DMA round

  // prologue: DMA chunk 0 (24 KB E tile = 3 rounds) + kv chunk 0
  GLOAD_LDS16(tE + t16,        &sB[0][t16]);
  GLOAD_LDS16(tE + 4096 + t16, &sB[0][4096 + t16]);
  GLOAD_LDS16(tE + 8192 + t16, &sB[0][8192 + t16]);
  if (tid < 32) GLOAD_LDS16(Kvb + tid*4, &kvf[0][0][0] + tid*4);

  for (int tc = 0; tc < NS; tc += TKC) {
    int ci = tc >> 5;
    int cb = ci & 1;
    __syncthreads();   // barrier 1: chunk-ci DMA drained; prev MFMA reads done

    // --- P-gen: 8 p's for (sP, t = qP*8 + j); kvf reads wave-broadcast ---
    {
      unsigned hi4[4], lo4[4];
      float dsum = 0.f;
#pragma unroll
      for (int jp = 0; jp < 4; jp++) {
        float4 ka = *(const float4*)&kvf[cb][qP*8 + 2*jp][0];
        float4 kb = *(const float4*)&kvf[cb][qP*8 + 2*jp + 1][0];
        float arga = qv.x*ka.x + qv.y*ka.y + qv.z*ka.z + qv.w*ka.w;
        float argb = qv.x*kb.x + qv.y*kb.y + qv.z*kb.z + qv.w*kb.w;
        float pa = __expf(arga), pb = __expf(argb);
        dsum += pa + pb;
        unsigned bpa = __float_as_uint(pa), bpb = __float_as_uint(pb);
        float lpa = pa - __uint_as_float(bpa & 0xFFFF0000u);
        float lpb = pb - __uint_as_float(bpb & 0xFFFF0000u);
        hi4[jp] = pack_bf16(bpa, bpb);
        lo4[jp] = pack_bf16(__float_as_uint(lpa), __float_as_uint(lpb));
      }
      den_acc += dsum;
      int offA = sP*32 + ((qP ^ ((sP>>1)&3))*8);
      *(uint4*)&sA[offA]        = make_uint4(hi4[0],hi4[1],hi4[2],hi4[3]);
      *(uint4*)&sA[4096 + offA] = make_uint4(lo4[0],lo4[1],lo4[2],lo4[3]);
    }

    __syncthreads();   // barrier 2: sA ready

    // --- DMA next chunk (drains at next barrier 1, behind MFMA) ---
    if (tc + TKC < NS) {
      const unsigned short* nE = tE + (size_t)(ci+1)*12288;
      int nb = cb ^ 1;
      GLOAD_LDS16(nE + t16,        &sB[nb][t16]);
      GLOAD_LDS16(nE + 4096 + t16, &sB[nb][4096 + t16]);
      GLOAD_LDS16(nE + 8192 + t16, &sB[nb][8192 + t16]);
      if (tid < 32) GLOAD_LDS16(Kvb + (size_t)(tc+TKC)*4 + tid*4, &kvf[nb][0][0] + tid*4);
    }

    // --- MFMA: wave (sh,hh) computes 64x48 via 4x3 tiles of 16x16x32, 3 passes ---
    short8 ah[4], al[4];
#pragma unroll
    for (int i = 0; i < 4; i++) {
      int srow = sh*64 + i*16 + m16;
      ah[i] = __builtin_bit_cast(short8, *(const uint4*)&sA[srow*TKC + cidx]);
      al[i] = __builtin_bit_cast(short8, *(const uint4*)&sA[4096 + srow*TKC + cidx]);
    }
#pragma unroll
    for (int jt = 0; jt < 3; jt++) {
      int hrow = hh*48 + jt*16 + m16;
      short8 bh_ = __builtin_bit_cast(short8, *(const uint4*)&sB[cb][hrow*TKC + cidx]);
      short8 bl_ = __builtin_bit_cast(short8, *(const uint4*)&sB[cb][6144 + hrow*TKC + cidx]);
#pragma unroll
      for (int i = 0; i < 4; i++) {
        acc[i][jt] = __builtin_amdgcn_mfma_f32_16x16x32_bf16(ah[i], bl_, acc[i][jt], 0, 0, 0);
        acc[i][jt] = __builtin_amdgcn_mfma_f32_16x16x32_bf16(al[i], bh_, acc[i][jt], 0, 0, 0);
        acc[i][jt] = __builtin_amdgcn_mfma_f32_16x16x32_bf16(ah[i], bh_, acc[i][jt], 0, 0, 0);
      }
    }
  }

  // --- denominator reduce ---
  __syncthreads();
  denp[sP*4 + qP] = den_acc;
  __syncthreads();
  if (tid < 128) {
    dfin[tid] = denp[tid*4] + denp[tid*4+1] + denp[tid*4+2] + denp[tid*4+3];
  }
  __syncthreads();

  // --- epilogue: C/D layout col=lane&15, row=(lane>>4)*4+reg; scale by 1/den ---
  float* ob = out + ((size_t)(b*NS + sblk*128))*NH + hblk*192;
#pragma unroll
  for (int i = 0; i < 4; i++) {
#pragma unroll
    for (int reg = 0; reg < 4; reg++) {
      int row = q16*4 + reg;
      int s_loc = sh*64 + i*16 + row;
      float invd = 1.0f / dfin[s_loc];
#pragma unroll
      for (int jt = 0; jt < 3; jt++) {
        int h_loc = hh*48 + jt*16 + m16;
        ob[(size_t)s_loc*NH + h_loc] = acc[i][jt][reg] * invd;
      }
    }
  }
}

extern "C" void kernel_launch(void* const* d_in, const int* in_sizes, int n_in,
                              void* d_out, int out_size, void* d_ws, size_t ws_size,
                              hipStream_t stream) {
  const float* E   = (const float*)d_in[0];
  const float* Wq  = (const float*)d_in[1];
  const float* bq  = (const float*)d_in[2];
  const float* Wk  = (const float*)d_in[3];
  const float* bk  = (const float*)d_in[4];
  const float* wts = (const float*)d_in[5];
  float* ws  = (float*)d_ws;
  float* Vre = ws;                       // 256 f
  float* Vim = ws + 256;                 // 256 f
  float* Qv  = ws + 512;                 // NPOS*4 f
  float* Kv  = Qv + (size_t)NPOS*4;      // NPOS*4 f
  unsigned short* ET = (unsigned short*)(Kv + (size_t)NPOS*4);  // 50.3 MB
  float* out = (float*)d_out;

  epre_kernel<<<dim3(64, 4, 8), 384, 0, stream>>>(E, wts, Vre, Vim, ET);
  proj_vqc_kernel<<<1024, 256, 0, stream>>>(E, Wq, bq, Wk, bk, Vre, Vim, Qv, Kv);
  attn_kernel<<<dim3(16, 4, 8), 512, 0, stream>>>(ET, Qv, Kv, out);
}